// Round 10
// baseline (46.827 us; speedup 1.0000x reference)
//
#include <hip/hip_runtime.h>

// RegionLoss v10 = v8 minus the block-wide convoy:
//  - 512 thr/block, 1 cell/thread, 4 blocks/CU = 32 waves/CU (HW max)
//  - each WAVE stages its own 1216-word target chunk via gl16 -> no
//    cross-wave LDS sharing -> NO __syncthreads before compute; each wave
//    drains its own loads with s_waitcnt vmcnt(0) and proceeds independently
//  - 32 scalar channel loads batched + pinned (2x16-op asm)
//  - block partial -> one float atomicAdd to d_out (finalize folded away)

namespace {

constexpr int kNC = 13;
constexpr int kCh = 32;                  // 19 + kNC channels per anchor
constexpr int kH = 76, kW = 76;
constexpr int kSP = kH * kW;             // 5776
constexpr int kCells = 32 * 5 * kSP;     // 924160
constexpr int kTPB = 512;
constexpr int kBlocks = kCells / kTPB;   // 1805 (exact)
constexpr int kWW = 64 * 19;             // 1216 words: one wave's chunk
constexpr int kTW = kTPB * 19;           // 9728 words = 38912 B

__device__ __forceinline__ void gl16(const float* g, float* l) {
  __builtin_amdgcn_global_load_lds(
      (const __attribute__((address_space(1))) void*)g,
      (__attribute__((address_space(3))) void*)l, 16, 0, 0);
}

__global__ __launch_bounds__(512, 8)
void region_loss_v10(const float* __restrict__ out,
                     const float* __restrict__ tgt,
                     float* __restrict__ result)
{
  __shared__ __align__(16) float tl[kTW];    // 38912 B
  __shared__ float wsum[8];

  const int tid  = threadIdx.x;
  const int blk  = blockIdx.x;
  const int lane = tid & 63;
  const int w    = tid >> 6;

  // ---- 32 scalar channel loads issued first ----
  const int n = blk * kTPB + tid;
  const int q = n / kSP;                     // b*NA + a
  const int s = n - q * kSP;
  const float* op = out + (size_t)q * kCh * kSP + s;

  float ch[kCh];
#pragma unroll
  for (int c = 0; c < kCh; ++c) ch[c] = op[(size_t)c * kSP];

  // ---- async stage: wave w's OWN 1216-word target chunk (304 float4) ----
  const float* tg = tgt + (size_t)blk * kTW + w * kWW;
  float* lb = &tl[w * kWW];
#pragma unroll
  for (int k = 0; k < 4; ++k)
    gl16(tg + (size_t)(k * 64 + lane) * 4, lb + k * 256);
  if (lane < 48)
    gl16(tg + (size_t)(256 + lane) * 4, lb + 1024);

  // ---- pin channel values (batched issue, no per-load serialization) ----
  asm volatile("" :
      "+v"(ch[0]), "+v"(ch[1]), "+v"(ch[2]), "+v"(ch[3]),
      "+v"(ch[4]), "+v"(ch[5]), "+v"(ch[6]), "+v"(ch[7]),
      "+v"(ch[8]), "+v"(ch[9]), "+v"(ch[10]), "+v"(ch[11]),
      "+v"(ch[12]), "+v"(ch[13]), "+v"(ch[14]), "+v"(ch[15]));
  asm volatile("" :
      "+v"(ch[16]), "+v"(ch[17]), "+v"(ch[18]), "+v"(ch[19]),
      "+v"(ch[20]), "+v"(ch[21]), "+v"(ch[22]), "+v"(ch[23]),
      "+v"(ch[24]), "+v"(ch[25]), "+v"(ch[26]), "+v"(ch[27]),
      "+v"(ch[28]), "+v"(ch[29]), "+v"(ch[30]), "+v"(ch[31]));

  // ---- per-wave drain: NO block barrier (no cross-wave LDS sharing) ----
  __builtin_amdgcn_sched_barrier(0);
  asm volatile("s_waitcnt vmcnt(0)" ::: "memory");
  __builtin_amdgcn_sched_barrier(0);

  // ---- per-cell loss ----
  const int hh = s / kW;
  const float fh = (float)hh;
  const float fw = (float)(s - hh * kW);

  const int rb = tid * 19;                   // within own wave's chunk
  const float clsf = tl[rb];
  const bool obj = (clsf != 0.f);

  float tcf = 0.f, lcd = 0.f;
#pragma unroll
  for (int i = 0; i < 9; ++i) {
    float xv = ch[14 + 2 * i];
    float yv = ch[15 + 2 * i];
    if (i == 0) {
      xv = __builtin_amdgcn_rcpf(1.f + __expf(-xv));
      yv = __builtin_amdgcn_rcpf(1.f + __expf(-yv));
    }
    const float gx = tl[rb + 1 + 2 * i];
    const float gy = tl[rb + 2 + 2 * i];
    const float tx = gx - fw;
    const float ty = gy - fh;
    const float dx = tx - (xv + fw);
    const float dy = ty - (yv + fh);
    const float dt = sqrtf(dx * dx + dy * dy);
    if (dt < 30.f) tcf += __expf(2.f - dt * (1.f / 15.f));
    const float ex = xv - tx;
    const float ey = yv - ty;
    lcd += ex * ex + ey * ey;
  }

  const float d = ch[kNC] - tcf * (1.f / 9.f);
  float loss = 0.005f * d * d;               // 0.5*(0.1*(conf-tconf))^2
  if (obj) loss += 0.5f * lcd;

  if (obj) {
    float mx = ch[0];
#pragma unroll
    for (int c = 1; c < kNC; ++c) mx = fmaxf(mx, ch[c]);
    float se = 0.f;
#pragma unroll
    for (int c = 0; c < kNC; ++c) se += __expf(ch[c] - mx);
    const int tc = (int)clsf;
    float sel = 0.f;
#pragma unroll
    for (int c = 0; c < kNC; ++c) sel += (c == tc) ? ch[c] : 0.f;
    loss += -(sel - mx - __logf(se));
  }

  // ---- reduce: wave shuffle -> LDS -> one float atomic per block ----
#pragma unroll
  for (int off = 32; off > 0; off >>= 1)
    loss += __shfl_down(loss, off, 64);

  if (lane == 0) wsum[w] = loss;
  __syncthreads();
  if (tid == 0) {
    float b = 0.f;
#pragma unroll
    for (int i = 0; i < 8; ++i) b += wsum[i];
    atomicAdd(result, b);
  }
}

}  // namespace

extern "C" void kernel_launch(void* const* d_in, const int* in_sizes, int n_in,
                              void* d_out, int out_size, void* d_ws, size_t ws_size,
                              hipStream_t stream) {
  const float* output = (const float*)d_in[0];
  const float* target = (const float*)d_in[1];
  float* result = (float*)d_out;

  hipMemsetAsync(result, 0, sizeof(float), stream);

  region_loss_v10<<<kBlocks, kTPB, 0, stream>>>(output, target, result);
}

// Round 11
// 45.943 us; speedup vs baseline: 1.0192x; 1.0192x over previous
//
#include <hip/hip_runtime.h>

// RegionLoss v11: wave-granular units, no block convoy, full occupancy.
//  - 2048 blocks x 256 thr; LDS 19.5KB -> 8 blocks/CU = 32 waves/CU
//  - 8192 independent waves; wave g processes 64-cell units g and g+8192
//    (14440 units). No block barrier in the work path: each wave stages its
//    OWN 1216-word target chunk via gl16, drains its own vmcnt(0), computes.
//  - 32 channel dword loads batched + pinned (2x16-op asm)
//  - lgkmcnt(0) guard before re-staging the reused per-wave LDS chunk
//  - block partials -> 64 line-spread double slots in d_ws (+finalize)

namespace {

constexpr int kNC = 13;
constexpr int kCh = 32;                  // 19 + kNC channels per anchor
constexpr int kH = 76, kW = 76;
constexpr int kSP = kH * kW;             // 5776
constexpr int kCells = 32 * 5 * kSP;     // 924160
constexpr int kUnits = kCells / 64;      // 14440 wave-units
constexpr int kGrid  = 2048;             // 8 blocks/CU exact; 8192 waves
constexpr int kWW = 64 * 19;             // 1216 words: one wave's chunk

__device__ __forceinline__ void gl16(const float* g, float* l) {
  __builtin_amdgcn_global_load_lds(
      (const __attribute__((address_space(1))) void*)g,
      (__attribute__((address_space(3))) void*)l, 16, 0, 0);
}

// Process one 64-cell unit u on this wave. lb = wave's private LDS chunk.
__device__ __forceinline__ float unitLoss(int u, int lane,
                                          const float* __restrict__ out,
                                          const float* __restrict__ tgt,
                                          float* __restrict__ lb)
{
  const int n = u * 64 + lane;
  const int q = n / kSP;                 // b*NA + a
  const int s = n - q * kSP;
  const float* op = out + (size_t)q * kCh * kSP + s;

  // 32 channel dword loads (each 256B/wave, 4-line perfect)
  float ch[kCh];
#pragma unroll
  for (int c = 0; c < kCh; ++c) ch[c] = op[(size_t)c * kSP];

  // wave's own 1216-word target chunk: 304 float4 = 4 full + 48-lane gl16
  const float* tg = tgt + (size_t)u * kWW;
#pragma unroll
  for (int k = 0; k < 4; ++k)
    gl16(tg + (size_t)(k * 64 + lane) * 4, lb + k * 256);
  if (lane < 48)
    gl16(tg + (size_t)(256 + lane) * 4, lb + 1024);

  // pin channel values: batched issue, no per-load serialization
  asm volatile("" :
      "+v"(ch[0]), "+v"(ch[1]), "+v"(ch[2]), "+v"(ch[3]),
      "+v"(ch[4]), "+v"(ch[5]), "+v"(ch[6]), "+v"(ch[7]),
      "+v"(ch[8]), "+v"(ch[9]), "+v"(ch[10]), "+v"(ch[11]),
      "+v"(ch[12]), "+v"(ch[13]), "+v"(ch[14]), "+v"(ch[15]));
  asm volatile("" :
      "+v"(ch[16]), "+v"(ch[17]), "+v"(ch[18]), "+v"(ch[19]),
      "+v"(ch[20]), "+v"(ch[21]), "+v"(ch[22]), "+v"(ch[23]),
      "+v"(ch[24]), "+v"(ch[25]), "+v"(ch[26]), "+v"(ch[27]),
      "+v"(ch[28]), "+v"(ch[29]), "+v"(ch[30]), "+v"(ch[31]));

  // per-wave drain; no block barrier (chunk is wave-private)
  __builtin_amdgcn_sched_barrier(0);
  asm volatile("s_waitcnt vmcnt(0)" ::: "memory");
  __builtin_amdgcn_sched_barrier(0);

  const int hh = s / kW;
  const float fh = (float)hh;
  const float fw = (float)(s - hh * kW);

  const int rb = lane * 19;              // within wave's chunk
  const float clsf = lb[rb];
  const bool obj = (clsf != 0.f);

  float tcf = 0.f, lcd = 0.f;
#pragma unroll
  for (int i = 0; i < 9; ++i) {
    float xv = ch[14 + 2 * i];
    float yv = ch[15 + 2 * i];
    if (i == 0) {
      xv = __builtin_amdgcn_rcpf(1.f + __expf(-xv));
      yv = __builtin_amdgcn_rcpf(1.f + __expf(-yv));
    }
    const float gx = lb[rb + 1 + 2 * i];
    const float gy = lb[rb + 2 + 2 * i];
    const float tx = gx - fw;
    const float ty = gy - fh;
    const float dx = tx - (xv + fw);
    const float dy = ty - (yv + fh);
    const float dt = sqrtf(dx * dx + dy * dy);
    if (dt < 30.f) tcf += __expf(2.f - dt * (1.f / 15.f));
    const float ex = xv - tx;
    const float ey = yv - ty;
    lcd += ex * ex + ey * ey;
  }

  const float d = ch[kNC] - tcf * (1.f / 9.f);
  float loss = 0.005f * d * d;           // 0.5*(0.1*(conf-tconf))^2
  if (obj) loss += 0.5f * lcd;

  if (obj) {
    float mx = ch[0];
#pragma unroll
    for (int c = 1; c < kNC; ++c) mx = fmaxf(mx, ch[c]);
    float se = 0.f;
#pragma unroll
    for (int c = 0; c < kNC; ++c) se += __expf(ch[c] - mx);
    const int tc = (int)clsf;
    float sel = 0.f;
#pragma unroll
    for (int c = 0; c < kNC; ++c) sel += (c == tc) ? ch[c] : 0.f;
    loss += -(sel - mx - __logf(se));
  }
  return loss;
}

__global__ __launch_bounds__(256, 8)
void region_loss_v11(const float* __restrict__ out,
                     const float* __restrict__ tgt,
                     double* __restrict__ acc)
{
  __shared__ __align__(16) float tl[4 * kWW];   // 19456 B (4 waves)
  __shared__ float wsum[4];

  const int tid  = threadIdx.x;
  const int lane = tid & 63;
  const int w    = tid >> 6;
  float* lb = &tl[w * kWW];

  const int g = blockIdx.x * 4 + w;             // global wave id, < 8192

  float loss = unitLoss(g, lane, out, tgt, lb);

  const int u1 = g + 8192;
  if (u1 < kUnits) {
    // guard: all ds_reads of unit0 retired before LDS-DMA re-stages chunk
    asm volatile("s_waitcnt lgkmcnt(0)" ::: "memory");
    __builtin_amdgcn_sched_barrier(0);
    loss += unitLoss(u1, lane, out, tgt, lb);
  }

  // ---- reduce: wave shuffle -> LDS -> one double atomic per block ----
#pragma unroll
  for (int off = 32; off > 0; off >>= 1)
    loss += __shfl_down(loss, off, 64);

  if (lane == 0) wsum[w] = loss;
  __syncthreads();
  if (tid == 0) {
    const float b = wsum[0] + wsum[1] + wsum[2] + wsum[3];
    atomicAdd(&acc[(blockIdx.x & 63) * 8], (double)b);   // line-spread slots
  }
}

__global__ void finalize_kernel(const double* __restrict__ acc,
                                float* __restrict__ outv)
{
  const int lane = threadIdx.x;
  double v = acc[lane * 8];
#pragma unroll
  for (int off = 32; off > 0; off >>= 1)
    v += __shfl_down(v, off, 64);
  if (lane == 0) outv[0] = (float)v;
}

}  // namespace

extern "C" void kernel_launch(void* const* d_in, const int* in_sizes, int n_in,
                              void* d_out, int out_size, void* d_ws, size_t ws_size,
                              hipStream_t stream) {
  const float* output = (const float*)d_in[0];
  const float* target = (const float*)d_in[1];
  double* acc = (double*)d_ws;

  hipMemsetAsync(acc, 0, 64 * 8 * sizeof(double), stream);

  region_loss_v11<<<kGrid, 256, 0, stream>>>(output, target, acc);
  finalize_kernel<<<1, 64, 0, stream>>>(acc, (float*)d_out);
}

// Round 12
// 41.337 us; speedup vs baseline: 1.1328x; 1.1114x over previous
//
#include <hip/hip_runtime.h>

// RegionLoss v8 (restored best): max TLP + staged target + batched loads.
//  - 512 thr/block, 1 cell/thread: slab 38.9KB serves 8 waves ->
//    4 blocks/CU = 32 waves/CU (HW max wave slots), VGPR<=64
//  - 32 scalar channel loads issued first, then 38 gl16 slab loads,
//    then two 16-op pins (batched waits), single drain at barrier
//  - block partials -> 64 line-spread double slots (no single-address atomic)
// Measured: 41.7 us = 188 MB / 41.7 us = 4.5 TB/s effective (L3-resident),
// pinned by per-CU outstanding-line limit x L3 latency (see session notes).

namespace {

constexpr int kNC = 13;
constexpr int kCh = 32;                  // 19 + kNC channels per anchor
constexpr int kH = 76, kW = 76;
constexpr int kSP = kH * kW;             // 5776
constexpr int kCells = 32 * 5 * kSP;     // 924160
constexpr int kTPB = 512;
constexpr int kBlocks = kCells / kTPB;   // 1805 (exact)
constexpr int kTW = kTPB * 19;           // 9728 words = 38912 B
constexpr int kF4 = kTW / 4;             // 2432 float4s = 38 wave-instrs

__device__ __forceinline__ void gl16(const float* g, float* l) {
  __builtin_amdgcn_global_load_lds(
      (const __attribute__((address_space(1))) void*)g,
      (__attribute__((address_space(3))) void*)l, 16, 0, 0);
}

__global__ __launch_bounds__(512, 8)
void region_loss_v8(const float* __restrict__ out,
                    const float* __restrict__ tgt,
                    double* __restrict__ acc)
{
  __shared__ __align__(16) float tl[kTW];    // 38912 B
  __shared__ float wsum[8];

  const int tid  = threadIdx.x;
  const int blk  = blockIdx.x;
  const int lane = tid & 63;
  const int w    = tid >> 6;

  // ---- 32 scalar channel loads issued first (oldest in vmcnt FIFO) ----
  const int n = blk * kTPB + tid;
  const int q = n / kSP;                     // b*NA + a
  const int s = n - q * kSP;
  const float* op = out + (size_t)q * kCh * kSP + s;

  float ch[kCh];
#pragma unroll
  for (int c = 0; c < kCh; ++c) ch[c] = op[(size_t)c * kSP];

  // ---- async stage target slab: 38 x 1KB wave-instrs across 8 waves ----
  const float* tg = tgt + (size_t)blk * kTW;
#pragma unroll
  for (int k = 0; k < 5; ++k) {
    const int i4 = (k * 8 + w) * 64;         // wave-uniform float4 base
    if (i4 < kF4)
      gl16(tg + (size_t)(i4 + lane) * 4, &tl[(size_t)i4 * 4]);
  }

  // ---- pin channel values: force "loaded before barrier", batched waits ----
  asm volatile("" :
      "+v"(ch[0]), "+v"(ch[1]), "+v"(ch[2]), "+v"(ch[3]),
      "+v"(ch[4]), "+v"(ch[5]), "+v"(ch[6]), "+v"(ch[7]),
      "+v"(ch[8]), "+v"(ch[9]), "+v"(ch[10]), "+v"(ch[11]),
      "+v"(ch[12]), "+v"(ch[13]), "+v"(ch[14]), "+v"(ch[15]));
  asm volatile("" :
      "+v"(ch[16]), "+v"(ch[17]), "+v"(ch[18]), "+v"(ch[19]),
      "+v"(ch[20]), "+v"(ch[21]), "+v"(ch[22]), "+v"(ch[23]),
      "+v"(ch[24]), "+v"(ch[25]), "+v"(ch[26]), "+v"(ch[27]),
      "+v"(ch[28]), "+v"(ch[29]), "+v"(ch[30]), "+v"(ch[31]));

  __syncthreads();                           // drain + slab visible

  // ---- per-cell loss ----
  const int hh = s / kW;
  const float fh = (float)hh;
  const float fw = (float)(s - hh * kW);

  const int rb = tid * 19;                   // stride-19: 2-way (free)
  const float clsf = tl[rb];
  const bool obj = (clsf != 0.f);

  float tcf = 0.f, lcd = 0.f;
#pragma unroll
  for (int i = 0; i < 9; ++i) {
    float xv = ch[14 + 2 * i];
    float yv = ch[15 + 2 * i];
    if (i == 0) {
      xv = __builtin_amdgcn_rcpf(1.f + __expf(-xv));
      yv = __builtin_amdgcn_rcpf(1.f + __expf(-yv));
    }
    const float gx = tl[rb + 1 + 2 * i];
    const float gy = tl[rb + 2 + 2 * i];
    const float tx = gx - fw;
    const float ty = gy - fh;
    const float dx = tx - (xv + fw);
    const float dy = ty - (yv + fh);
    const float dt = sqrtf(dx * dx + dy * dy);
    if (dt < 30.f) tcf += __expf(2.f - dt * (1.f / 15.f));
    const float ex = xv - tx;
    const float ey = yv - ty;
    lcd += ex * ex + ey * ey;
  }

  const float d = ch[kNC] - tcf * (1.f / 9.f);
  float loss = 0.005f * d * d;               // 0.5*(0.1*(conf-tconf))^2
  if (obj) loss += 0.5f * lcd;

  if (obj) {
    float mx = ch[0];
#pragma unroll
    for (int c = 1; c < kNC; ++c) mx = fmaxf(mx, ch[c]);
    float se = 0.f;
#pragma unroll
    for (int c = 0; c < kNC; ++c) se += __expf(ch[c] - mx);
    const int tc = (int)clsf;
    float sel = 0.f;
#pragma unroll
    for (int c = 0; c < kNC; ++c) sel += (c == tc) ? ch[c] : 0.f;
    loss += -(sel - mx - __logf(se));
  }

  // ---- reduce: wave shuffle -> LDS -> one atomic/block to spread slot ----
#pragma unroll
  for (int off = 32; off > 0; off >>= 1)
    loss += __shfl_down(loss, off, 64);

  if (lane == 0) wsum[w] = loss;
  __syncthreads();
  if (tid == 0) {
    float b = 0.f;
#pragma unroll
    for (int i = 0; i < 8; ++i) b += wsum[i];
    atomicAdd(&acc[(blk & 63) * 8], (double)b);   // 64 line-spread slots
  }
}

__global__ void finalize_kernel(const double* __restrict__ acc,
                                float* __restrict__ outv)
{
  const int lane = threadIdx.x;
  double v = acc[lane * 8];
#pragma unroll
  for (int off = 32; off > 0; off >>= 1)
    v += __shfl_down(v, off, 64);
  if (lane == 0) outv[0] = (float)v;
}

}  // namespace

extern "C" void kernel_launch(void* const* d_in, const int* in_sizes, int n_in,
                              void* d_out, int out_size, void* d_ws, size_t ws_size,
                              hipStream_t stream) {
  const float* output = (const float*)d_in[0];
  const float* target = (const float*)d_in[1];
  double* acc = (double*)d_ws;

  hipMemsetAsync(acc, 0, 64 * 8 * sizeof(double), stream);

  region_loss_v8<<<kBlocks, kTPB, 0, stream>>>(output, target, acc);
  finalize_kernel<<<1, 64, 0, stream>>>(acc, (float*)d_out);
}